// Round 1
// baseline (64233.881 us; speedup 1.0000x reference)
//
#include <hip/hip_runtime.h>
#include <hip/hip_bf16.h>
#include <math.h>

#define EPSV 1e-5f

__device__ __forceinline__ int isgn(float x) { return (x > 0.f) - (x < 0.f); }

// ---------------- conv1: fp32 input x sign(W) + b, then sign -> int8 ----------------
__global__ __launch_bounds__(256) void conv1_sign_kernel(
    const float* __restrict__ x, const float* __restrict__ Wt,
    const float* __restrict__ bias, signed char* __restrict__ out) {
    const int Ci = 3, H = 224, Wd = 224, Co = 96, OH = 55, OW = 55, K = 11, S = 4, P = 2;
    const int N = 128;
    int idx = blockIdx.x * blockDim.x + threadIdx.x;
    const int total = N * Co * OH * OW;
    if (idx >= total) return;
    int ow = idx % OW;
    int t = idx / OW;
    int oh = t % OH; t /= OH;
    int co = t % Co;
    int n = t / Co;
    int ih0 = oh * S - P, iw0 = ow * S - P;
    int khlo = max(0, -ih0), khhi = min(K, H - ih0);
    int kwlo = max(0, -iw0), kwhi = min(K, Wd - iw0);
    float acc = bias[co];
    for (int ci = 0; ci < Ci; ++ci) {
        const float* xp = x + ((size_t)(n * Ci + ci) * H) * Wd;
        const float* wp = Wt + ((size_t)(co * Ci + ci) * K) * K;
        for (int kh = khlo; kh < khhi; ++kh) {
            const float* xr = xp + (size_t)(ih0 + kh) * Wd + iw0;
            const float* wr = wp + kh * K;
            for (int kw = kwlo; kw < kwhi; ++kw) {
                acc += (float)isgn(wr[kw]) * xr[kw];
            }
        }
    }
    out[idx] = (signed char)isgn(acc);
}

// ---------------- binary conv: int8 {-1,0,1} acts x sign(W), int accumulate ----------------
template <int K, int P>
__global__ __launch_bounds__(256) void bconv_kernel(
    const signed char* __restrict__ in, const float* __restrict__ Wt,
    const float* __restrict__ bias, float* __restrict__ out,
    int N, int Ci, int Co, int H, int W) {
    int idx = blockIdx.x * blockDim.x + threadIdx.x;
    int total = N * Co * H * W;
    if (idx >= total) return;
    int ow = idx % W;
    int t = idx / W;
    int oh = t % H; t /= H;
    int co = t % Co;
    int n = t / Co;
    int ih0 = oh - P, iw0 = ow - P;
    int khlo = max(0, -ih0), khhi = min(K, H - ih0);
    int kwlo = max(0, -iw0), kwhi = min(K, W - iw0);
    int acc = 0;
    for (int ci = 0; ci < Ci; ++ci) {
        const signed char* ip = in + ((size_t)(n * Ci + ci) * H) * W;
        const float* wp = Wt + ((size_t)(co * Ci + ci) * K) * K;
        for (int kh = khlo; kh < khhi; ++kh) {
            const signed char* ir = ip + (ih0 + kh) * W + iw0;
            const float* wr = wp + kh * K;
            for (int kw = kwlo; kw < kwhi; ++kw) {
                acc += isgn(wr[kw]) * (int)ir[kw];
            }
        }
    }
    out[idx] = (float)acc + bias[co];
}

// ---------------- maxpool3s2 over int8 signs, then BN, then sign -> int8 ----------------
__global__ __launch_bounds__(256) void pool_bn_sign_i8(
    const signed char* __restrict__ in,
    const float* __restrict__ g, const float* __restrict__ cb,
    const float* __restrict__ m, const float* __restrict__ v,
    signed char* __restrict__ out, int N, int C, int H, int W, int OH, int OW) {
    int idx = blockIdx.x * blockDim.x + threadIdx.x;
    int total = N * C * OH * OW;
    if (idx >= total) return;
    int ow = idx % OW;
    int t = idx / OW;
    int oh = t % OH; t /= OH;
    int ch = t % C;
    int n = t / C;
    const signed char* ip = in + ((size_t)(n * C + ch) * H + oh * 2) * W + ow * 2;
    int mx = -127;
    #pragma unroll
    for (int kh = 0; kh < 3; ++kh)
        #pragma unroll
        for (int kw = 0; kw < 3; ++kw)
            mx = max(mx, (int)ip[kh * W + kw]);
    float y = g[ch] * ((float)mx - m[ch]) * rsqrtf(v[ch] + EPSV) + cb[ch];
    out[idx] = (signed char)isgn(y);
}

// ---------------- maxpool3s2 over fp32, then BN, then sign -> int8 ----------------
__global__ __launch_bounds__(256) void pool_bn_sign_f32(
    const float* __restrict__ in,
    const float* __restrict__ g, const float* __restrict__ cb,
    const float* __restrict__ m, const float* __restrict__ v,
    signed char* __restrict__ out, int N, int C, int H, int W, int OH, int OW) {
    int idx = blockIdx.x * blockDim.x + threadIdx.x;
    int total = N * C * OH * OW;
    if (idx >= total) return;
    int ow = idx % OW;
    int t = idx / OW;
    int oh = t % OH; t /= OH;
    int ch = t % C;
    int n = t / C;
    const float* ip = in + ((size_t)(n * C + ch) * H + oh * 2) * W + ow * 2;
    float mx = -INFINITY;
    #pragma unroll
    for (int kh = 0; kh < 3; ++kh)
        #pragma unroll
        for (int kw = 0; kw < 3; ++kw)
            mx = fmaxf(mx, ip[kh * W + kw]);
    float y = g[ch] * (mx - m[ch]) * rsqrtf(v[ch] + EPSV) + cb[ch];
    out[idx] = (signed char)isgn(y);
}

// ---------------- elementwise BN then sign -> int8 (HW=1 gives bn1d) ----------------
__global__ __launch_bounds__(256) void bn_sign_kernel(
    const float* __restrict__ in,
    const float* __restrict__ g, const float* __restrict__ cb,
    const float* __restrict__ m, const float* __restrict__ v,
    signed char* __restrict__ out, int total, int HW, int C) {
    int idx = blockIdx.x * blockDim.x + threadIdx.x;
    if (idx >= total) return;
    int ch = (idx / HW) % C;
    float y = g[ch] * (in[idx] - m[ch]) * rsqrtf(v[ch] + EPSV) + cb[ch];
    out[idx] = (signed char)isgn(y);
}

// ---------------- FC: one block per output feature o; thread = batch row n ----------------
// int8 act row dot sign(W[o,:]), weight signs staged in LDS, exact int accumulate.
__global__ __launch_bounds__(128) void fc_kernel(
    const signed char* __restrict__ act, const float* __restrict__ Wt,
    const float* __restrict__ bias, float* __restrict__ out, int I, int O) {
    __shared__ signed char ws[128];
    int o = blockIdx.x;
    int n = threadIdx.x;  // 0..127 == batch
    const float* wrow = Wt + (size_t)o * I;
    const signed char* arow = act + (size_t)n * I;
    int acc = 0;
    for (int i0 = 0; i0 < I; i0 += 128) {
        __syncthreads();
        ws[n] = (signed char)isgn(wrow[i0 + n]);
        __syncthreads();
        #pragma unroll 16
        for (int j = 0; j < 128; ++j)
            acc += (int)ws[j] * (int)arow[i0 + j];
    }
    out[(size_t)n * O + o] = (float)acc + bias[o];
}

// ---------------- BN8 + log_softmax, one block per batch row ----------------
__global__ __launch_bounds__(256) void bn_lsm_kernel(
    const float* __restrict__ in,
    const float* __restrict__ g, const float* __restrict__ cb,
    const float* __restrict__ m, const float* __restrict__ v,
    float* __restrict__ out, int O) {
    int n = blockIdx.x;
    __shared__ float buf[1000];
    __shared__ float red[256];
    int tid = threadIdx.x;
    float lmax = -INFINITY;
    for (int o = tid; o < O; o += 256) {
        float xv = in[(size_t)n * O + o];
        float y = g[o] * (xv - m[o]) * rsqrtf(v[o] + EPSV) + cb[o];
        buf[o] = y;
        lmax = fmaxf(lmax, y);
    }
    red[tid] = lmax;
    __syncthreads();
    for (int s = 128; s > 0; s >>= 1) {
        if (tid < s) red[tid] = fmaxf(red[tid], red[tid + s]);
        __syncthreads();
    }
    float mx = red[0];
    __syncthreads();
    float lsum = 0.f;
    for (int o = tid; o < O; o += 256) lsum += expf(buf[o] - mx);
    red[tid] = lsum;
    __syncthreads();
    for (int s = 128; s > 0; s >>= 1) {
        if (tid < s) red[tid] += red[tid + s];
        __syncthreads();
    }
    float lse = mx + logf(red[0]);
    for (int o = tid; o < O; o += 256) out[(size_t)n * O + o] = buf[o] - lse;
}

extern "C" void kernel_launch(void* const* d_in, const int* in_sizes, int n_in,
                              void* d_out, int out_size, void* d_ws, size_t ws_size,
                              hipStream_t stream) {
    const float* x = (const float*)d_in[0];
    // layer L (1..8), param k: 0=W 1=b 2=g 3=c 4=m 5=v
    auto L = [&](int layer, int k) -> const float* {
        return (const float*)d_in[1 + (layer - 1) * 6 + k];
    };

    char* ws = (char*)d_ws;
    float* A = (float*)(ws + 0);                              // 95,551,488 B fp32 scratch
    signed char* S1 = (signed char*)(ws + 95551488);          // 37,171,200 B sign(conv1)
    signed char* B1 = (signed char*)(ws + 95551488 + 37171200); // 9,437,184 B
    signed char* B2 = B1 + 9437184;                           // 9,437,184 B
    // total ws usage: 151,597,056 B

    const int TB = 256;

    // conv1 + sign -> S1 [128,96,55,55]
    conv1_sign_kernel<<<37171200 / TB, TB, 0, stream>>>(x, L(1, 0), L(1, 1), S1);
    // pool + bn1 + sign -> B1 [128,96,27,27]
    pool_bn_sign_i8<<<8957952 / TB, TB, 0, stream>>>(S1, L(1, 2), L(1, 3), L(1, 4), L(1, 5),
                                                     B1, 128, 96, 55, 55, 27, 27);
    // conv2 (K5 P2) -> A [128,256,27,27]
    bconv_kernel<5, 2><<<23887872 / TB, TB, 0, stream>>>(B1, L(2, 0), L(2, 1), A,
                                                         128, 96, 256, 27, 27);
    // pool + bn2 + sign -> B2 [128,256,13,13]
    pool_bn_sign_f32<<<5537792 / TB, TB, 0, stream>>>(A, L(2, 2), L(2, 3), L(2, 4), L(2, 5),
                                                      B2, 128, 256, 27, 27, 13, 13);
    // conv3 (K3 P1) -> A [128,384,13,13]
    bconv_kernel<3, 1><<<8306688 / TB, TB, 0, stream>>>(B2, L(3, 0), L(3, 1), A,
                                                        128, 256, 384, 13, 13);
    // bn3 + sign -> B1
    bn_sign_kernel<<<8306688 / TB, TB, 0, stream>>>(A, L(3, 2), L(3, 3), L(3, 4), L(3, 5),
                                                    B1, 8306688, 169, 384);
    // conv4 -> A [128,384,13,13]
    bconv_kernel<3, 1><<<8306688 / TB, TB, 0, stream>>>(B1, L(4, 0), L(4, 1), A,
                                                        128, 384, 384, 13, 13);
    // bn4 + sign -> B2
    bn_sign_kernel<<<8306688 / TB, TB, 0, stream>>>(A, L(4, 2), L(4, 3), L(4, 4), L(4, 5),
                                                    B2, 8306688, 169, 384);
    // conv5 -> A [128,256,13,13]
    bconv_kernel<3, 1><<<5537792 / TB, TB, 0, stream>>>(B2, L(5, 0), L(5, 1), A,
                                                        128, 384, 256, 13, 13);
    // pool + bn5 + sign -> B1 [128,256,6,6] == [128,9216]
    pool_bn_sign_f32<<<1179648 / TB, TB, 0, stream>>>(A, L(5, 2), L(5, 3), L(5, 4), L(5, 5),
                                                      B1, 128, 256, 13, 13, 6, 6);
    // fc6 -> A [128,4096]
    fc_kernel<<<4096, 128, 0, stream>>>(B1, L(6, 0), L(6, 1), A, 9216, 4096);
    // bn6 + sign -> B2
    bn_sign_kernel<<<524288 / TB, TB, 0, stream>>>(A, L(6, 2), L(6, 3), L(6, 4), L(6, 5),
                                                   B2, 524288, 1, 4096);
    // fc7 -> A [128,4096]
    fc_kernel<<<4096, 128, 0, stream>>>(B2, L(7, 0), L(7, 1), A, 4096, 4096);
    // bn7 + sign -> B1
    bn_sign_kernel<<<524288 / TB, TB, 0, stream>>>(A, L(7, 2), L(7, 3), L(7, 4), L(7, 5),
                                                   B1, 524288, 1, 4096);
    // fc8 -> A [128,1000]
    fc_kernel<<<1000, 128, 0, stream>>>(B1, L(8, 0), L(8, 1), A, 4096, 1000);
    // bn8 + log_softmax -> d_out [128,1000]
    bn_lsm_kernel<<<128, 256, 0, stream>>>(A, L(8, 2), L(8, 3), L(8, 4), L(8, 5),
                                           (float*)d_out, 1000);
}

// Round 2
// 13564.328 us; speedup vs baseline: 4.7355x; 4.7355x over previous
//
#include <hip/hip_runtime.h>
#include <hip/hip_bf16.h>
#include <math.h>

#define EPSV 1e-5f
typedef unsigned long long u64;

__device__ __forceinline__ int isgn(float x) { return (x > 0.f) - (x < 0.f); }
__device__ __forceinline__ float bnf(float x, float g, float c, float m, float v) {
    return g * (x - m) * rsqrtf(v + EPSV) + c;
}

// =================== weight pack kernels ===================

// sign(W1) -> fp32 +-1
__global__ __launch_bounds__(256) void pack_w1s(const float* __restrict__ W,
                                                float* __restrict__ out, int n) {
    int i = blockIdx.x * blockDim.x + threadIdx.x;
    if (i < n) out[i] = (W[i] > 0.f) ? 1.f : -1.f;
}

// conv weights OIHW -> packed u64 [Co, K, K, CW], bit b of word cw <-> ci = cw*64+b
template <int K, int CW>
__global__ __launch_bounds__(256) void pack_wc(const float* __restrict__ W,
                                               u64* __restrict__ out, int Ci, int Co) {
    int wid = blockIdx.x * 4 + (threadIdx.x >> 6);
    int b = threadIdx.x & 63;
    int total = Co * K * K * CW;
    if (wid >= total) return;
    int cw = wid % CW;
    int t = wid / CW;
    int kw = t % K; t /= K;
    int kh = t % K;
    int co = t / K;
    int ci = cw * 64 + b;
    int bit = 0;
    if (ci < Ci) bit = W[(((size_t)co * Ci + ci) * K + kh) * K + kw] > 0.f;
    u64 mask = __ballot(bit);
    if (b == 0) out[wid] = mask;
}

// fc6 weights [4096, 9216] where col = c*36 + p (p = h*6+w), act word j = p*4 + cw.
// output TRANSPOSED: [144, 4096]
__global__ __launch_bounds__(256) void pack_wfc6(const float* __restrict__ W,
                                                 u64* __restrict__ out) {
    int wid = blockIdx.x * 4 + (threadIdx.x >> 6);  // wid = o*144 + j
    int b = threadIdx.x & 63;
    int o = wid / 144;
    int j = wid % 144;
    int c = (j & 3) * 64 + b;
    int p = j >> 2;
    float val = W[(size_t)o * 9216 + c * 36 + p];
    u64 mask = __ballot(val > 0.f);
    if (b == 0) out[(size_t)j * 4096 + o] = mask;
}

// fc7/fc8 weights [O, 4096], col = j*64+b. output transposed [64, O]
__global__ __launch_bounds__(256) void pack_wfc(const float* __restrict__ W,
                                                u64* __restrict__ out, int O) {
    int wid = blockIdx.x * 4 + (threadIdx.x >> 6);  // wid = o*64 + j
    int b = threadIdx.x & 63;
    if (wid >= O * 64) return;
    int o = wid >> 6;
    int j = wid & 63;
    float val = W[(size_t)o * 4096 + j * 64 + b];
    u64 mask = __ballot(val > 0.f);
    if (b == 0) out[(size_t)j * O + o] = mask;
}

// =================== conv1: fp32 x (+-1 weights), sign -> int8 NCHW ===================
__global__ __launch_bounds__(256) void conv1_sign_kernel(
    const float* __restrict__ x, const float* __restrict__ Ws,
    const float* __restrict__ bias, signed char* __restrict__ out) {
    const int Ci = 3, H = 224, Wd = 224, Co = 96, OH = 55, OW = 55, K = 11, S = 4, P = 2;
    const int N = 128;
    int idx = blockIdx.x * blockDim.x + threadIdx.x;
    const int total = N * Co * OH * OW;
    if (idx >= total) return;
    int ow = idx % OW;
    int t = idx / OW;
    int oh = t % OH; t /= OH;
    int co = t % Co;
    int n = t / Co;
    int ih0 = oh * S - P, iw0 = ow * S - P;
    int khlo = max(0, -ih0), khhi = min(K, H - ih0);
    int kwlo = max(0, -iw0), kwhi = min(K, Wd - iw0);
    float acc = bias[co];
    for (int ci = 0; ci < Ci; ++ci) {
        const float* xp = x + ((size_t)(n * Ci + ci) * H) * Wd;
        const float* wp = Ws + ((size_t)(co * Ci + ci) * K) * K;
        for (int kh = khlo; kh < khhi; ++kh) {
            const float* xr = xp + (size_t)(ih0 + kh) * Wd + iw0;
            const float* wr = wp + kh * K;
            for (int kw = kwlo; kw < kwhi; ++kw) {
                acc += wr[kw] * xr[kw];
            }
        }
    }
    out[idx] = (signed char)isgn(acc);
}

// =================== pool(3s2) over int8 NCHW signs + bn + sign -> packed ===================
// block = 128 threads (c = tid, valid < 96), grid = N*OH*OW
__global__ __launch_bounds__(128) void pool1_pack(
    const signed char* __restrict__ in,
    const float* __restrict__ g, const float* __restrict__ cb,
    const float* __restrict__ m, const float* __restrict__ v,
    u64* __restrict__ out) {
    const int C = 96, H = 55, W = 55, OW = 27, OH = 27;
    int bx = blockIdx.x;
    int ow = bx % OW;
    int t = bx / OW;
    int oh = t % OH;
    int n = t / OH;
    int c = threadIdx.x;
    int bit = 0;
    if (c < C) {
        const signed char* ip = in + ((size_t)(n * C + c) * H + oh * 2) * W + ow * 2;
        int mx = -127;
        #pragma unroll
        for (int kh = 0; kh < 3; ++kh)
            #pragma unroll
            for (int kw = 0; kw < 3; ++kw)
                mx = max(mx, (int)ip[kh * W + kw]);
        float y = bnf((float)mx, g[c], cb[c], m[c], v[c]);
        bit = y > 0.f;
    }
    u64 mask = __ballot(bit);
    if ((threadIdx.x & 63) == 0) out[(size_t)bx * 2 + (threadIdx.x >> 6)] = mask;
}

// =================== pool(3s2) over fp32 NCHW + bn + sign -> packed ===================
// block = C threads, grid = N*OH*OW, out [n,oh,ow,cw]
__global__ __launch_bounds__(256) void pool_pack_f32(
    const float* __restrict__ in,
    const float* __restrict__ g, const float* __restrict__ cb,
    const float* __restrict__ m, const float* __restrict__ v,
    u64* __restrict__ out, int C, int H, int W, int OH, int OW) {
    int bx = blockIdx.x;
    int ow = bx % OW;
    int t = bx / OW;
    int oh = t % OH;
    int n = t / OH;
    int c = threadIdx.x;
    const float* ip = in + ((size_t)(n * C + c) * H + oh * 2) * W + ow * 2;
    float mx = -INFINITY;
    #pragma unroll
    for (int kh = 0; kh < 3; ++kh)
        #pragma unroll
        for (int kw = 0; kw < 3; ++kw)
            mx = fmaxf(mx, ip[kh * W + kw]);
    float y = bnf(mx, g[c], cb[c], m[c], v[c]);
    u64 mask = __ballot(y > 0.f);
    if ((c & 63) == 0) out[(size_t)bx * (C >> 6) + (c >> 6)] = mask;
}

// =================== bn + sign -> packed (no pool), fp32 NCHW in ===================
// block = C threads, grid = N*HW
__global__ __launch_bounds__(384) void bn_pack_f32(
    const float* __restrict__ in,
    const float* __restrict__ g, const float* __restrict__ cb,
    const float* __restrict__ m, const float* __restrict__ v,
    u64* __restrict__ out, int C, int HW) {
    int bx = blockIdx.x;
    int p = bx % HW;
    int n = bx / HW;
    int c = threadIdx.x;
    float val = in[((size_t)n * C + c) * HW + p];
    float y = bnf(val, g[c], cb[c], m[c], v[c]);
    u64 mask = __ballot(y > 0.f);
    if ((c & 63) == 0) out[(size_t)bx * (C >> 6) + (c >> 6)] = mask;
}

// =================== bn + sign -> packed for fc activations [128, 4096] ===================
// grid (4096/256, 128)
__global__ __launch_bounds__(256) void bn_pack_fc(
    const float* __restrict__ in,
    const float* __restrict__ g, const float* __restrict__ cb,
    const float* __restrict__ m, const float* __restrict__ v,
    u64* __restrict__ out) {
    int c = blockIdx.x * 256 + threadIdx.x;
    int n = blockIdx.y;
    float val = in[(size_t)n * 4096 + c];
    float y = bnf(val, g[c], cb[c], m[c], v[c]);
    u64 mask = __ballot(y > 0.f);
    if ((threadIdx.x & 63) == 0) out[(size_t)n * 64 + (c >> 6)] = mask;
}

// =================== binary conv via xnor-popcount ===================
// act u64 [N,H,W,CW], wgt u64 [Co,K,K,CW], out fp32 NCHW [N,Co,H,W]
template <int K, int P, int CW>
__global__ __launch_bounds__(256) void bconv_bit(
    const u64* __restrict__ act, const u64* __restrict__ wgt,
    const float* __restrict__ bias, float* __restrict__ out,
    int N, int Ci, int Co, int H, int W) {
    int p = blockIdx.x * 256 + threadIdx.x;
    if (p >= N * H * W) return;
    int ow = p % W;
    int t = p / W;
    int oh = t % H;
    int n = t / H;
    int co = blockIdx.y;
    const u64* wrow = wgt + (size_t)co * K * K * CW;
    int mism = 0, nval = 0;
    #pragma unroll
    for (int kh = 0; kh < K; ++kh) {
        int ih = oh - P + kh;
        if ((unsigned)ih >= (unsigned)H) continue;
        #pragma unroll
        for (int kw = 0; kw < K; ++kw) {
            int iw = ow - P + kw;
            if ((unsigned)iw >= (unsigned)W) continue;
            const u64* ap = act + ((size_t)(n * H + ih) * W + iw) * CW;
            const u64* wp = wrow + (kh * K + kw) * CW;
            #pragma unroll
            for (int cw = 0; cw < CW; ++cw)
                mism += __popcll(ap[cw] ^ wp[cw]);
            nval++;
        }
    }
    float acc = (float)(nval * Ci - 2 * mism) + bias[co];
    out[((size_t)(n * Co + co) * H + oh) * W + ow] = acc;
}

// =================== binary FC via xnor-popcount ===================
// actw [128, IW], wgtT [IW, O], out fp32 [128, O]; Cin = IW*64
__global__ __launch_bounds__(256) void fc_bit(
    const u64* __restrict__ actw, const u64* __restrict__ wgtT,
    const float* __restrict__ bias, float* __restrict__ out, int IW, int O) {
    int o = blockIdx.x * 256 + threadIdx.x;
    if (o >= O) return;
    int n0 = blockIdx.y * 8;
    const u64* ap = actw + (size_t)n0 * IW;
    int acc[8];
    #pragma unroll
    for (int r = 0; r < 8; ++r) acc[r] = 0;
    for (int w = 0; w < IW; ++w) {
        u64 wv = wgtT[(size_t)w * O + o];
        #pragma unroll
        for (int r = 0; r < 8; ++r)
            acc[r] += __popcll(ap[(size_t)r * IW + w] ^ wv);
    }
    float b = bias[o];
    #pragma unroll
    for (int r = 0; r < 8; ++r)
        out[(size_t)(n0 + r) * O + o] = (float)(IW * 64 - 2 * acc[r]) + b;
}

// =================== BN8 + log_softmax, one block per batch row ===================
__global__ __launch_bounds__(256) void bn_lsm_kernel(
    const float* __restrict__ in,
    const float* __restrict__ g, const float* __restrict__ cb,
    const float* __restrict__ m, const float* __restrict__ v,
    float* __restrict__ out, int O) {
    int n = blockIdx.x;
    __shared__ float buf[1000];
    __shared__ float red[256];
    int tid = threadIdx.x;
    float lmax = -INFINITY;
    for (int o = tid; o < O; o += 256) {
        float y = bnf(in[(size_t)n * O + o], g[o], cb[o], m[o], v[o]);
        buf[o] = y;
        lmax = fmaxf(lmax, y);
    }
    red[tid] = lmax;
    __syncthreads();
    for (int s = 128; s > 0; s >>= 1) {
        if (tid < s) red[tid] = fmaxf(red[tid], red[tid + s]);
        __syncthreads();
    }
    float mx = red[0];
    __syncthreads();
    float lsum = 0.f;
    for (int o = tid; o < O; o += 256) lsum += expf(buf[o] - mx);
    red[tid] = lsum;
    __syncthreads();
    for (int s = 128; s > 0; s >>= 1) {
        if (tid < s) red[tid] += red[tid + s];
        __syncthreads();
    }
    float lse = mx + logf(red[0]);
    for (int o = tid; o < O; o += 256) out[(size_t)n * O + o] = buf[o] - lse;
}

extern "C" void kernel_launch(void* const* d_in, const int* in_sizes, int n_in,
                              void* d_out, int out_size, void* d_ws, size_t ws_size,
                              hipStream_t stream) {
    const float* x = (const float*)d_in[0];
    auto L = [&](int layer, int k) -> const float* {
        return (const float*)d_in[1 + (layer - 1) * 6 + k];
    };

    char* ws = (char*)d_ws;
    float* A        = (float*)(ws + 0);              // 95,551,488 fp32 NCHW scratch
    signed char* S1 = (signed char*)(ws + 95551488); // 37,171,200 conv1 signs NCHW
    u64* P1  = (u64*)(ws + 132722688);  // [128,27,27,2]   1,492,992
    u64* P2  = (u64*)(ws + 134215680);  // [128,13,13,4]     692,224
    u64* P3a = (u64*)(ws + 134907904);  // [128,13,13,6]   1,038,336
    u64* P3b = (u64*)(ws + 135946240);  // [128,13,13,6]   1,038,336
    u64* P5  = (u64*)(ws + 136984576);  // [128,144]         147,456
    u64* F7  = (u64*)(ws + 137132032);  // [128,64]           65,536
    u64* F8  = (u64*)(ws + 137197568);  // [128,64]           65,536
    u64* Wc2 = (u64*)(ws + 137263104);  // [256,5,5,2]       102,400
    u64* Wc3 = (u64*)(ws + 137365504);  // [384,3,3,4]       110,592
    u64* Wc4 = (u64*)(ws + 137476096);  // [384,3,3,6]       165,888
    u64* Wc5 = (u64*)(ws + 137641984);  // [256,3,3,6]       110,592
    u64* Wf6 = (u64*)(ws + 137752576);  // [144,4096]      4,718,592
    u64* Wf7 = (u64*)(ws + 142471168);  // [64,4096]       2,097,152
    u64* Wf8 = (u64*)(ws + 144568320);  // [64,1000]         512,000
    float* W1s = (float*)(ws + 145080320); // [96,3,11,11]    139,392

    // ---- weight packs ----
    pack_w1s<<<137, 256, 0, stream>>>(L(1, 0), W1s, 34848);
    pack_wc<5, 2><<<3200, 256, 0, stream>>>(L(2, 0), Wc2, 96, 256);
    pack_wc<3, 4><<<3456, 256, 0, stream>>>(L(3, 0), Wc3, 256, 384);
    pack_wc<3, 6><<<5184, 256, 0, stream>>>(L(4, 0), Wc4, 384, 384);
    pack_wc<3, 6><<<3456, 256, 0, stream>>>(L(5, 0), Wc5, 384, 256);
    pack_wfc6<<<147456, 256, 0, stream>>>(L(6, 0), Wf6);
    pack_wfc<<<65536, 256, 0, stream>>>(L(7, 0), Wf7, 4096);
    pack_wfc<<<16000, 256, 0, stream>>>(L(8, 0), Wf8, 1000);

    // ---- network ----
    // conv1 + sign -> S1 [128,96,55,55] NCHW int8
    conv1_sign_kernel<<<145200, 256, 0, stream>>>(x, W1s, L(1, 1), S1);
    // pool + bn1 + sign + pack -> P1 [128,27,27,2]
    pool1_pack<<<93312, 128, 0, stream>>>(S1, L(1, 2), L(1, 3), L(1, 4), L(1, 5), P1);
    // conv2 (K5,P2) -> A [128,256,27,27]
    {
        dim3 g((128 * 27 * 27 + 255) / 256, 256);
        bconv_bit<5, 2, 2><<<g, 256, 0, stream>>>(P1, Wc2, L(2, 1), A, 128, 96, 256, 27, 27);
    }
    // pool + bn2 + sign + pack -> P2 [128,13,13,4]
    pool_pack_f32<<<128 * 13 * 13, 256, 0, stream>>>(A, L(2, 2), L(2, 3), L(2, 4), L(2, 5),
                                                     P2, 256, 27, 27, 13, 13);
    // conv3 -> A [128,384,13,13]
    {
        dim3 g((128 * 13 * 13 + 255) / 256, 384);
        bconv_bit<3, 1, 4><<<g, 256, 0, stream>>>(P2, Wc3, L(3, 1), A, 128, 256, 384, 13, 13);
    }
    // bn3 + sign + pack -> P3a
    bn_pack_f32<<<128 * 169, 384, 0, stream>>>(A, L(3, 2), L(3, 3), L(3, 4), L(3, 5),
                                               P3a, 384, 169);
    // conv4 -> A [128,384,13,13]
    {
        dim3 g((128 * 13 * 13 + 255) / 256, 384);
        bconv_bit<3, 1, 6><<<g, 256, 0, stream>>>(P3a, Wc4, L(4, 1), A, 128, 384, 384, 13, 13);
    }
    // bn4 + sign + pack -> P3b
    bn_pack_f32<<<128 * 169, 384, 0, stream>>>(A, L(4, 2), L(4, 3), L(4, 4), L(4, 5),
                                               P3b, 384, 169);
    // conv5 -> A [128,256,13,13]
    {
        dim3 g((128 * 13 * 13 + 255) / 256, 256);
        bconv_bit<3, 1, 6><<<g, 256, 0, stream>>>(P3b, Wc5, L(5, 1), A, 128, 384, 256, 13, 13);
    }
    // pool + bn5 + sign + pack -> P5 [128,144] (fc6 input)
    pool_pack_f32<<<128 * 6 * 6, 256, 0, stream>>>(A, L(5, 2), L(5, 3), L(5, 4), L(5, 5),
                                                   P5, 256, 13, 13, 6, 6);
    // fc6 -> A [128,4096]
    {
        dim3 g(16, 16);
        fc_bit<<<g, 256, 0, stream>>>(P5, Wf6, L(6, 1), A, 144, 4096);
    }
    // bn6 + sign + pack -> F7
    {
        dim3 g(16, 128);
        bn_pack_fc<<<g, 256, 0, stream>>>(A, L(6, 2), L(6, 3), L(6, 4), L(6, 5), F7);
    }
    // fc7 -> A [128,4096]
    {
        dim3 g(16, 16);
        fc_bit<<<g, 256, 0, stream>>>(F7, Wf7, L(7, 1), A, 64, 4096);
    }
    // bn7 + sign + pack -> F8
    {
        dim3 g(16, 128);
        bn_pack_fc<<<g, 256, 0, stream>>>(A, L(7, 2), L(7, 3), L(7, 4), L(7, 5), F8);
    }
    // fc8 -> A [128,1000]
    {
        dim3 g(4, 16);
        fc_bit<<<g, 256, 0, stream>>>(F8, Wf8, L(8, 1), A, 64, 1000);
    }
    // bn8 + log_softmax -> d_out
    bn_lsm_kernel<<<128, 256, 0, stream>>>(A, L(8, 2), L(8, 3), L(8, 4), L(8, 5),
                                           (float*)d_out, 1000);
}

// Round 3
// 1944.397 us; speedup vs baseline: 33.0354x; 6.9761x over previous
//
#include <hip/hip_runtime.h>
#include <hip/hip_bf16.h>
#include <math.h>

#define EPSV 1e-5f
typedef unsigned long long u64;

__device__ __forceinline__ int isgn(float x) { return (x > 0.f) - (x < 0.f); }
__device__ __forceinline__ float bnf(float x, float g, float c, float m, float v) {
    return g * (x - m) * rsqrtf(v + EPSV) + c;
}

// =================== conv1 prep: pad input, transpose-pack signed weights ===================

// Xp[n][ci][228][228], interior (ihp-2, iwp-2) = x, border 0
__global__ __launch_bounds__(256) void pad_x(const float* __restrict__ x,
                                             float* __restrict__ Xp) {
    int idx = blockIdx.x * 256 + threadIdx.x;
    const int total = 128 * 3 * 228 * 228;
    if (idx >= total) return;
    int iwp = idx % 228;
    int t = idx / 228;
    int ihp = t % 228;
    int nc = t / 228;  // n*3+ci
    int iw = iwp - 2, ih = ihp - 2;
    float v = 0.f;
    if ((unsigned)iw < 224u && (unsigned)ih < 224u)
        v = x[((size_t)nc * 224 + ih) * 224 + iw];
    Xp[idx] = v;
}

// W1 [96,3,11,11] -> Wp [6 cog][3 ci][11 kh][11 kw][16 co] as +-1 fp32
__global__ __launch_bounds__(256) void pack_w1t(const float* __restrict__ W,
                                                float* __restrict__ Wp) {
    int idx = blockIdx.x * 256 + threadIdx.x;
    const int total = 6 * 3 * 11 * 11 * 16;
    if (idx >= total) return;
    int j = idx % 16;
    int t = idx / 16;
    int kw = t % 11; t /= 11;
    int kh = t % 11; t /= 11;
    int ci = t % 3;
    int cog = t / 3;
    int co = cog * 16 + j;
    float w = W[(((size_t)co * 3 + ci) * 11 + kh) * 11 + kw];
    Wp[idx] = (w > 0.f) ? 1.f : -1.f;
}

// =================== conv1: register-tiled, 16 co per block, sign -> int8 NCHW ===================
// grid (128 n, 14 ohg, 6 cog), block 256 = 4 waves; wave -> oh row, lane -> ow
__global__ __launch_bounds__(256) void conv1_tile(
    const float* __restrict__ Xp, const float* __restrict__ Wp,
    const float* __restrict__ bias, signed char* __restrict__ S1) {
    const int Hp = 228, Wpad = 228, OH = 55, OW = 55;
    int n = blockIdx.x, ohg = blockIdx.y, cog = blockIdx.z;
    int lane = threadIdx.x & 63;
    int oh = ohg * 4 + (threadIdx.x >> 6);
    bool act = (lane < OW) && (oh < OH);
    int owc = min(lane, OW - 1);
    int ohc = min(oh, OH - 1);

    float acc[16];
    #pragma unroll
    for (int j = 0; j < 16; ++j) acc[j] = 0.f;

    const float* __restrict__ wbase = Wp + (size_t)cog * (3 * 11 * 11 * 16);

    for (int ci = 0; ci < 3; ++ci) {
        const float* xrow0 = Xp + ((size_t)(n * 3 + ci) * Hp + ohc * 4) * Wpad + owc * 4;
        const float* __restrict__ wci = wbase + ci * (11 * 11 * 16);
        for (int kh = 0; kh < 11; ++kh) {
            const float4* xr = (const float4*)(xrow0 + kh * Wpad);
            float4 a = xr[0], b = xr[1], c = xr[2];
            float xv[12] = {a.x, a.y, a.z, a.w, b.x, b.y, b.z, b.w, c.x, c.y, c.z, c.w};
            const float* __restrict__ wk = wci + kh * (11 * 16);
            #pragma unroll
            for (int kw = 0; kw < 11; ++kw) {
                #pragma unroll
                for (int j = 0; j < 16; ++j)
                    acc[j] += wk[kw * 16 + j] * xv[kw];
            }
        }
    }

    if (act) {
        size_t base = ((size_t)(n * 96 + cog * 16) * OH + oh) * OW + lane;
        #pragma unroll
        for (int j = 0; j < 16; ++j) {
            float a = acc[j] + bias[cog * 16 + j];
            S1[base + (size_t)j * (OH * OW)] = (signed char)isgn(a);
        }
    }
}

// =================== weight pack kernels (binary layers) ===================

template <int K, int CW>
__global__ __launch_bounds__(256) void pack_wc(const float* __restrict__ W,
                                               u64* __restrict__ out, int Ci, int Co) {
    int wid = blockIdx.x * 4 + (threadIdx.x >> 6);
    int b = threadIdx.x & 63;
    int total = Co * K * K * CW;
    if (wid >= total) return;
    int cw = wid % CW;
    int t = wid / CW;
    int kw = t % K; t /= K;
    int kh = t % K;
    int co = t / K;
    int ci = cw * 64 + b;
    int bit = 0;
    if (ci < Ci) bit = W[(((size_t)co * Ci + ci) * K + kh) * K + kw] > 0.f;
    u64 mask = __ballot(bit);
    if (b == 0) out[wid] = mask;
}

__global__ __launch_bounds__(256) void pack_wfc6(const float* __restrict__ W,
                                                 u64* __restrict__ out) {
    int wid = blockIdx.x * 4 + (threadIdx.x >> 6);  // wid = o*144 + j
    int b = threadIdx.x & 63;
    int o = wid / 144;
    int j = wid % 144;
    int c = (j & 3) * 64 + b;
    int p = j >> 2;
    float val = W[(size_t)o * 9216 + c * 36 + p];
    u64 mask = __ballot(val > 0.f);
    if (b == 0) out[(size_t)j * 4096 + o] = mask;
}

__global__ __launch_bounds__(256) void pack_wfc(const float* __restrict__ W,
                                                u64* __restrict__ out, int O) {
    int wid = blockIdx.x * 4 + (threadIdx.x >> 6);  // wid = o*64 + j
    int b = threadIdx.x & 63;
    if (wid >= O * 64) return;
    int o = wid >> 6;
    int j = wid & 63;
    float val = W[(size_t)o * 4096 + j * 64 + b];
    u64 mask = __ballot(val > 0.f);
    if (b == 0) out[(size_t)j * O + o] = mask;
}

// =================== pool(3s2) over int8 NCHW signs + bn + sign -> packed ===================
__global__ __launch_bounds__(128) void pool1_pack(
    const signed char* __restrict__ in,
    const float* __restrict__ g, const float* __restrict__ cb,
    const float* __restrict__ m, const float* __restrict__ v,
    u64* __restrict__ out) {
    const int C = 96, H = 55, W = 55, OW = 27, OH = 27;
    int bx = blockIdx.x;
    int ow = bx % OW;
    int t = bx / OW;
    int oh = t % OH;
    int n = t / OH;
    int c = threadIdx.x;
    int bit = 0;
    if (c < C) {
        const signed char* ip = in + ((size_t)(n * C + c) * H + oh * 2) * W + ow * 2;
        int mx = -127;
        #pragma unroll
        for (int kh = 0; kh < 3; ++kh)
            #pragma unroll
            for (int kw = 0; kw < 3; ++kw)
                mx = max(mx, (int)ip[kh * W + kw]);
        float y = bnf((float)mx, g[c], cb[c], m[c], v[c]);
        bit = y > 0.f;
    }
    u64 mask = __ballot(bit);
    if ((threadIdx.x & 63) == 0) out[(size_t)bx * 2 + (threadIdx.x >> 6)] = mask;
}

// =================== pool(3s2) over fp32 NCHW + bn + sign -> packed ===================
__global__ __launch_bounds__(256) void pool_pack_f32(
    const float* __restrict__ in,
    const float* __restrict__ g, const float* __restrict__ cb,
    const float* __restrict__ m, const float* __restrict__ v,
    u64* __restrict__ out, int C, int H, int W, int OH, int OW) {
    int bx = blockIdx.x;
    int ow = bx % OW;
    int t = bx / OW;
    int oh = t % OH;
    int n = t / OH;
    int c = threadIdx.x;
    const float* ip = in + ((size_t)(n * C + c) * H + oh * 2) * W + ow * 2;
    float mx = -INFINITY;
    #pragma unroll
    for (int kh = 0; kh < 3; ++kh)
        #pragma unroll
        for (int kw = 0; kw < 3; ++kw)
            mx = fmaxf(mx, ip[kh * W + kw]);
    float y = bnf(mx, g[c], cb[c], m[c], v[c]);
    u64 mask = __ballot(y > 0.f);
    if ((c & 63) == 0) out[(size_t)bx * (C >> 6) + (c >> 6)] = mask;
}

// =================== bn + sign -> packed (no pool), fp32 NCHW in ===================
__global__ __launch_bounds__(384) void bn_pack_f32(
    const float* __restrict__ in,
    const float* __restrict__ g, const float* __restrict__ cb,
    const float* __restrict__ m, const float* __restrict__ v,
    u64* __restrict__ out, int C, int HW) {
    int bx = blockIdx.x;
    int p = bx % HW;
    int n = bx / HW;
    int c = threadIdx.x;
    float val = in[((size_t)n * C + c) * HW + p];
    float y = bnf(val, g[c], cb[c], m[c], v[c]);
    u64 mask = __ballot(y > 0.f);
    if ((c & 63) == 0) out[(size_t)bx * (C >> 6) + (c >> 6)] = mask;
}

// =================== bn + sign -> packed for fc activations [128, 4096] ===================
__global__ __launch_bounds__(256) void bn_pack_fc(
    const float* __restrict__ in,
    const float* __restrict__ g, const float* __restrict__ cb,
    const float* __restrict__ m, const float* __restrict__ v,
    u64* __restrict__ out) {
    int c = blockIdx.x * 256 + threadIdx.x;
    int n = blockIdx.y;
    float val = in[(size_t)n * 4096 + c];
    float y = bnf(val, g[c], cb[c], m[c], v[c]);
    u64 mask = __ballot(y > 0.f);
    if ((threadIdx.x & 63) == 0) out[(size_t)n * 64 + (c >> 6)] = mask;
}

// =================== binary conv via xnor-popcount ===================
template <int K, int P, int CW>
__global__ __launch_bounds__(256) void bconv_bit(
    const u64* __restrict__ act, const u64* __restrict__ wgt,
    const float* __restrict__ bias, float* __restrict__ out,
    int N, int Ci, int Co, int H, int W) {
    int p = blockIdx.x * 256 + threadIdx.x;
    if (p >= N * H * W) return;
    int ow = p % W;
    int t = p / W;
    int oh = t % H;
    int n = t / H;
    int co = blockIdx.y;
    const u64* wrow = wgt + (size_t)co * K * K * CW;
    int mism = 0, nval = 0;
    #pragma unroll
    for (int kh = 0; kh < K; ++kh) {
        int ih = oh - P + kh;
        if ((unsigned)ih >= (unsigned)H) continue;
        #pragma unroll
        for (int kw = 0; kw < K; ++kw) {
            int iw = ow - P + kw;
            if ((unsigned)iw >= (unsigned)W) continue;
            const u64* ap = act + ((size_t)(n * H + ih) * W + iw) * CW;
            const u64* wp = wrow + (kh * K + kw) * CW;
            #pragma unroll
            for (int cw = 0; cw < CW; ++cw)
                mism += __popcll(ap[cw] ^ wp[cw]);
            nval++;
        }
    }
    float acc = (float)(nval * Ci - 2 * mism) + bias[co];
    out[((size_t)(n * Co + co) * H + oh) * W + ow] = acc;
}

// =================== binary FC via xnor-popcount ===================
__global__ __launch_bounds__(256) void fc_bit(
    const u64* __restrict__ actw, const u64* __restrict__ wgtT,
    const float* __restrict__ bias, float* __restrict__ out, int IW, int O) {
    int o = blockIdx.x * 256 + threadIdx.x;
    if (o >= O) return;
    int n0 = blockIdx.y * 8;
    const u64* ap = actw + (size_t)n0 * IW;
    int acc[8];
    #pragma unroll
    for (int r = 0; r < 8; ++r) acc[r] = 0;
    for (int w = 0; w < IW; ++w) {
        u64 wv = wgtT[(size_t)w * O + o];
        #pragma unroll
        for (int r = 0; r < 8; ++r)
            acc[r] += __popcll(ap[(size_t)r * IW + w] ^ wv);
    }
    float b = bias[o];
    #pragma unroll
    for (int r = 0; r < 8; ++r)
        out[(size_t)(n0 + r) * O + o] = (float)(IW * 64 - 2 * acc[r]) + b;
}

// =================== BN8 + log_softmax, one block per batch row ===================
__global__ __launch_bounds__(256) void bn_lsm_kernel(
    const float* __restrict__ in,
    const float* __restrict__ g, const float* __restrict__ cb,
    const float* __restrict__ m, const float* __restrict__ v,
    float* __restrict__ out, int O) {
    int n = blockIdx.x;
    __shared__ float buf[1000];
    __shared__ float red[256];
    int tid = threadIdx.x;
    float lmax = -INFINITY;
    for (int o = tid; o < O; o += 256) {
        float y = bnf(in[(size_t)n * O + o], g[o], cb[o], m[o], v[o]);
        buf[o] = y;
        lmax = fmaxf(lmax, y);
    }
    red[tid] = lmax;
    __syncthreads();
    for (int s = 128; s > 0; s >>= 1) {
        if (tid < s) red[tid] = fmaxf(red[tid], red[tid + s]);
        __syncthreads();
    }
    float mx = red[0];
    __syncthreads();
    float lsum = 0.f;
    for (int o = tid; o < O; o += 256) lsum += expf(buf[o] - mx);
    red[tid] = lsum;
    __syncthreads();
    for (int s = 128; s > 0; s >>= 1) {
        if (tid < s) red[tid] += red[tid + s];
        __syncthreads();
    }
    float lse = mx + logf(red[0]);
    for (int o = tid; o < O; o += 256) out[(size_t)n * O + o] = buf[o] - lse;
}

extern "C" void kernel_launch(void* const* d_in, const int* in_sizes, int n_in,
                              void* d_out, int out_size, void* d_ws, size_t ws_size,
                              hipStream_t stream) {
    const float* x = (const float*)d_in[0];
    auto L = [&](int layer, int k) -> const float* {
        return (const float*)d_in[1 + (layer - 1) * 6 + k];
    };

    char* ws = (char*)d_ws;
    float* A        = (float*)(ws + 0);              // 95,551,488 fp32 NCHW scratch
    float* Xp       = A;                             // padded input aliases A (79,847,424 B)
    signed char* S1 = (signed char*)(ws + 95551488); // 37,171,200 conv1 signs NCHW
    u64* P1  = (u64*)(ws + 132722688);  // [128,27,27,2]   1,492,992
    u64* P2  = (u64*)(ws + 134215680);  // [128,13,13,4]     692,224
    u64* P3a = (u64*)(ws + 134907904);  // [128,13,13,6]   1,038,336
    u64* P3b = (u64*)(ws + 135946240);  // [128,13,13,6]   1,038,336
    u64* P5  = (u64*)(ws + 136984576);  // [128,144]         147,456
    u64* F7  = (u64*)(ws + 137132032);  // [128,64]           65,536
    u64* F8  = (u64*)(ws + 137197568);  // [128,64]           65,536
    u64* Wc2 = (u64*)(ws + 137263104);  // [256,5,5,2]       102,400
    u64* Wc3 = (u64*)(ws + 137365504);  // [384,3,3,4]       110,592
    u64* Wc4 = (u64*)(ws + 137476096);  // [384,3,3,6]       165,888
    u64* Wc5 = (u64*)(ws + 137641984);  // [256,3,3,6]       110,592
    u64* Wf6 = (u64*)(ws + 137752576);  // [144,4096]      4,718,592
    u64* Wf7 = (u64*)(ws + 142471168);  // [64,4096]       2,097,152
    u64* Wf8 = (u64*)(ws + 144568320);  // [64,1000]         512,000
    float* Wp1 = (float*)(ws + 145080320); // [6,3,11,11,16]  139,392

    // ---- weight packs / input pad ----
    pack_w1t<<<137, 256, 0, stream>>>(L(1, 0), Wp1);
    pad_x<<<(128 * 3 * 228 * 228 + 255) / 256, 256, 0, stream>>>(x, Xp);
    pack_wc<5, 2><<<3200, 256, 0, stream>>>(L(2, 0), Wc2, 96, 256);
    pack_wc<3, 4><<<3456, 256, 0, stream>>>(L(3, 0), Wc3, 256, 384);
    pack_wc<3, 6><<<5184, 256, 0, stream>>>(L(4, 0), Wc4, 384, 384);
    pack_wc<3, 6><<<3456, 256, 0, stream>>>(L(5, 0), Wc5, 384, 256);
    pack_wfc6<<<147456, 256, 0, stream>>>(L(6, 0), Wf6);
    pack_wfc<<<65536, 256, 0, stream>>>(L(7, 0), Wf7, 4096);
    pack_wfc<<<16000, 256, 0, stream>>>(L(8, 0), Wf8, 1000);

    // ---- network ----
    // conv1 + sign -> S1 [128,96,55,55] NCHW int8
    {
        dim3 g(128, 14, 6);
        conv1_tile<<<g, 256, 0, stream>>>(Xp, Wp1, L(1, 1), S1);
    }
    // pool + bn1 + sign + pack -> P1 [128,27,27,2]
    pool1_pack<<<93312, 128, 0, stream>>>(S1, L(1, 2), L(1, 3), L(1, 4), L(1, 5), P1);
    // conv2 (K5,P2) -> A [128,256,27,27]
    {
        dim3 g((128 * 27 * 27 + 255) / 256, 256);
        bconv_bit<5, 2, 2><<<g, 256, 0, stream>>>(P1, Wc2, L(2, 1), A, 128, 96, 256, 27, 27);
    }
    // pool + bn2 + sign + pack -> P2 [128,13,13,4]
    pool_pack_f32<<<128 * 13 * 13, 256, 0, stream>>>(A, L(2, 2), L(2, 3), L(2, 4), L(2, 5),
                                                     P2, 256, 27, 27, 13, 13);
    // conv3 -> A [128,384,13,13]
    {
        dim3 g((128 * 13 * 13 + 255) / 256, 384);
        bconv_bit<3, 1, 4><<<g, 256, 0, stream>>>(P2, Wc3, L(3, 1), A, 128, 256, 384, 13, 13);
    }
    // bn3 + sign + pack -> P3a
    bn_pack_f32<<<128 * 169, 384, 0, stream>>>(A, L(3, 2), L(3, 3), L(3, 4), L(3, 5),
                                               P3a, 384, 169);
    // conv4 -> A [128,384,13,13]
    {
        dim3 g((128 * 13 * 13 + 255) / 256, 384);
        bconv_bit<3, 1, 6><<<g, 256, 0, stream>>>(P3a, Wc4, L(4, 1), A, 128, 384, 384, 13, 13);
    }
    // bn4 + sign + pack -> P3b
    bn_pack_f32<<<128 * 169, 384, 0, stream>>>(A, L(4, 2), L(4, 3), L(4, 4), L(4, 5),
                                               P3b, 384, 169);
    // conv5 -> A [128,256,13,13]
    {
        dim3 g((128 * 13 * 13 + 255) / 256, 256);
        bconv_bit<3, 1, 6><<<g, 256, 0, stream>>>(P3b, Wc5, L(5, 1), A, 128, 384, 256, 13, 13);
    }
    // pool + bn5 + sign + pack -> P5 [128,144] (fc6 input)
    pool_pack_f32<<<128 * 6 * 6, 256, 0, stream>>>(A, L(5, 2), L(5, 3), L(5, 4), L(5, 5),
                                                   P5, 256, 13, 13, 6, 6);
    // fc6 -> A [128,4096]
    {
        dim3 g(16, 16);
        fc_bit<<<g, 256, 0, stream>>>(P5, Wf6, L(6, 1), A, 144, 4096);
    }
    // bn6 + sign + pack -> F7
    {
        dim3 g(16, 128);
        bn_pack_fc<<<g, 256, 0, stream>>>(A, L(6, 2), L(6, 3), L(6, 4), L(6, 5), F7);
    }
    // fc7 -> A [128,4096]
    {
        dim3 g(16, 16);
        fc_bit<<<g, 256, 0, stream>>>(F7, Wf7, L(7, 1), A, 64, 4096);
    }
    // bn7 + sign + pack -> F8
    {
        dim3 g(16, 128);
        bn_pack_fc<<<g, 256, 0, stream>>>(A, L(7, 2), L(7, 3), L(7, 4), L(7, 5), F8);
    }
    // fc8 -> A [128,1000]
    {
        dim3 g(4, 16);
        fc_bit<<<g, 256, 0, stream>>>(F8, Wf8, L(8, 1), A, 64, 1000);
    }
    // bn8 + log_softmax -> d_out
    bn_lsm_kernel<<<128, 256, 0, stream>>>(A, L(8, 2), L(8, 3), L(8, 4), L(8, 5),
                                           (float*)d_out, 1000);
}

// Round 4
// 1748.916 us; speedup vs baseline: 36.7278x; 1.1118x over previous
//
#include <hip/hip_runtime.h>
#include <hip/hip_bf16.h>
#include <math.h>

#define EPSV 1e-5f
typedef unsigned long long u64;
typedef unsigned short u16;

__device__ __forceinline__ float bnf(float x, float g, float c, float m, float v) {
    return g * (x - m) * rsqrtf(v + EPSV) + c;
}

// =================== conv1 prep: pad input, transpose-pack signed weights ===================

__global__ __launch_bounds__(256) void pad_x(const float* __restrict__ x,
                                             float* __restrict__ Xp) {
    int idx = blockIdx.x * 256 + threadIdx.x;
    const int total = 128 * 3 * 228 * 228;
    if (idx >= total) return;
    int iwp = idx % 228;
    int t = idx / 228;
    int ihp = t % 228;
    int nc = t / 228;
    int iw = iwp - 2, ih = ihp - 2;
    float v = 0.f;
    if ((unsigned)iw < 224u && (unsigned)ih < 224u)
        v = x[((size_t)nc * 224 + ih) * 224 + iw];
    Xp[idx] = v;
}

// W1 [96,3,11,11] -> Wp [6 cog][3 ci][11 kh][11 kw][16 co] as +-1 fp32
__global__ __launch_bounds__(256) void pack_w1t(const float* __restrict__ W,
                                                float* __restrict__ Wp) {
    int idx = blockIdx.x * 256 + threadIdx.x;
    const int total = 6 * 3 * 11 * 11 * 16;
    if (idx >= total) return;
    int j = idx % 16;
    int t = idx / 16;
    int kw = t % 11; t /= 11;
    int kh = t % 11; t /= 11;
    int ci = t % 3;
    int cog = t / 3;
    int co = cog * 16 + j;
    float w = W[(((size_t)co * 3 + ci) * 11 + kh) * 11 + kw];
    Wp[idx] = (w > 0.f) ? 1.f : -1.f;
}

// =================== conv1: register-tiled, 16 co/block -> u16 sign masks ===================
// grid (128 n, 14 ohg, 6 cog), block 256 = 4 waves; wave -> oh row, lane -> ow
// S1b: u16 [n][55][55][8] (cog 0..5 used)
__global__ __launch_bounds__(256) void conv1_tile(
    const float* __restrict__ Xp, const float* __restrict__ Wp,
    const float* __restrict__ bias, u16* __restrict__ S1b) {
    const int Hp = 228, Wpad = 228, OH = 55, OW = 55;
    int n = blockIdx.x, ohg = blockIdx.y, cog = blockIdx.z;
    int lane = threadIdx.x & 63;
    int oh = ohg * 4 + (threadIdx.x >> 6);
    bool act = (lane < OW) && (oh < OH);
    int owc = min(lane, OW - 1);
    int ohc = min(oh, OH - 1);

    float acc[16];
    #pragma unroll
    for (int j = 0; j < 16; ++j) acc[j] = 0.f;

    const float* __restrict__ wbase = Wp + (size_t)cog * (3 * 11 * 11 * 16);

    for (int ci = 0; ci < 3; ++ci) {
        const float* xrow0 = Xp + ((size_t)(n * 3 + ci) * Hp + ohc * 4) * Wpad + owc * 4;
        const float* __restrict__ wci = wbase + ci * (11 * 11 * 16);
        for (int kh = 0; kh < 11; ++kh) {
            const float4* xr = (const float4*)(xrow0 + kh * Wpad);
            float4 a = xr[0], b = xr[1], c = xr[2];
            float xv[12] = {a.x, a.y, a.z, a.w, b.x, b.y, b.z, b.w, c.x, c.y, c.z, c.w};
            const float* __restrict__ wk = wci + kh * (11 * 16);
            #pragma unroll
            for (int kw = 0; kw < 11; ++kw) {
                #pragma unroll
                for (int j = 0; j < 16; ++j)
                    acc[j] += wk[kw * 16 + j] * xv[kw];
            }
        }
    }

    if (act) {
        unsigned mask = 0;
        #pragma unroll
        for (int j = 0; j < 16; ++j)
            mask |= (acc[j] + bias[cog * 16 + j] > 0.f) ? (1u << j) : 0u;
        S1b[((size_t)(n * OH + oh) * OW + lane) * 8 + cog] = (u16)mask;
    }
}

// =================== pool1 + bn1 + sign: pure bitwise ===================
// grid = 128*27 (n, oh'), block 256, tid -> (ow' 0..26, cog 0..7)
// P1 u16-view: [n][27][27][8] == u64 [pixel][2]
__global__ __launch_bounds__(256) void pool1_bit(
    const u16* __restrict__ S1b,
    const float* __restrict__ g, const float* __restrict__ cb,
    const float* __restrict__ m, const float* __restrict__ v,
    u16* __restrict__ P1) {
    int n = blockIdx.x / 27;
    int ohp = blockIdx.x % 27;
    int tid = threadIdx.x;
    if (tid >= 216) return;
    int cog = tid & 7;
    int owp = tid >> 3;
    unsigned res = 0;
    if (cog < 6) {
        unsigned tp = 0, tn = 0;
        #pragma unroll
        for (int j = 0; j < 16; ++j) {
            int c = cog * 16 + j;
            float gg = g[c], cc = cb[c], mm = m[c], vv = v[c];
            tp |= (bnf(1.f, gg, cc, mm, vv) > 0.f) ? (1u << j) : 0u;
            tn |= (bnf(-1.f, gg, cc, mm, vv) > 0.f) ? (1u << j) : 0u;
        }
        unsigned mk = 0;
        #pragma unroll
        for (int kh = 0; kh < 3; ++kh)
            #pragma unroll
            for (int kw = 0; kw < 3; ++kw)
                mk |= S1b[((size_t)(n * 55 + 2 * ohp + kh) * 55 + 2 * owp + kw) * 8 + cog];
        res = (mk & tp) | (~mk & tn & 0xffffu);
    }
    P1[((size_t)(n * 27 + ohp) * 27 + owp) * 8 + cog] = (u16)res;
}

// =================== weight packs: conv (transposed), fc ===================

// OIHW -> wT u64 [kh][kw][cw][Co]
template <int K, int CW>
__global__ __launch_bounds__(256) void pack_wc_t(const float* __restrict__ W,
                                                 u64* __restrict__ out, int Ci, int Co) {
    int wid = blockIdx.x * 4 + (threadIdx.x >> 6);
    int b = threadIdx.x & 63;
    int total = Co * K * K * CW;
    if (wid >= total) return;
    int cw = wid % CW;
    int t = wid / CW;
    int kw = t % K; t /= K;
    int kh = t % K;
    int co = t / K;
    int ci = cw * 64 + b;
    int bit = 0;
    if (ci < Ci) bit = W[(((size_t)co * Ci + ci) * K + kh) * K + kw] > 0.f;
    u64 mask = __ballot(bit);
    if (b == 0) out[(size_t)(((kh * K + kw) * CW + cw)) * Co + co] = mask;
}

// fc6 [4096, 9216] (col = c*36+p) -> wgtT [144][4096]; coalesced read + LDS transpose
__global__ __launch_bounds__(256) void pack_wfc6_t(const float* __restrict__ W,
                                                   u64* __restrict__ out) {
    __shared__ float lds[256 * 37];
    int o = blockIdx.x;
    int tid = threadIdx.x;
    for (int i = tid; i < 9216; i += 256) {
        int c = i / 36, p = i - c * 36;
        lds[c * 37 + p] = W[(size_t)o * 9216 + i];
    }
    __syncthreads();
    int wave = tid >> 6, lane = tid & 63;
    for (int jj = wave; jj < 144; jj += 4) {
        int p = jj >> 2, cw = jj & 3;
        int bit = lds[(cw * 64 + lane) * 37 + p] > 0.f;
        u64 mask = __ballot(bit);
        if (lane == 0) out[(size_t)jj * 4096 + o] = mask;
    }
}

// fc7/fc8 [O, 4096] -> transposed [64][O] (reads coalesced: lane=b consecutive)
__global__ __launch_bounds__(256) void pack_wfc(const float* __restrict__ W,
                                                u64* __restrict__ out, int O) {
    int wid = blockIdx.x * 4 + (threadIdx.x >> 6);  // wid = o*64 + j
    int b = threadIdx.x & 63;
    if (wid >= O * 64) return;
    int o = wid >> 6;
    int j = wid & 63;
    float val = W[(size_t)o * 4096 + j * 64 + b];
    u64 mask = __ballot(val > 0.f);
    if (b == 0) out[(size_t)j * O + o] = mask;
}

// =================== binary conv: co-as-lane, weights in VGPR, act uniform ===================
// act u64 [n][H][W][CW]; wT u64 [kh][kw][cw][CO]; out fp32 NHWC [n][H][W][CO]
template <int K, int P, int CW, int HW, int W, int CO, int PIX, int CI>
__global__ __launch_bounds__(CO) void bconv_co(
    const u64* __restrict__ act, const u64* __restrict__ wT,
    const float* __restrict__ bias, float* __restrict__ out) {
    const int H = HW / W;
    int co = threadIdx.x;
    int n = blockIdx.y;
    int p0 = blockIdx.x * PIX;
    u64 wreg[K * K * CW];
    #pragma unroll
    for (int t = 0; t < K * K * CW; ++t) wreg[t] = wT[(size_t)t * CO + co];
    float b = bias[co];
    #pragma unroll
    for (int p = 0; p < PIX; ++p) {
        int pix = p0 + p;
        if (pix >= HW) break;
        int oh = pix / W, ow = pix - oh * W;
        int mism = 0, nval = 0;
        #pragma unroll
        for (int kh = 0; kh < K; ++kh) {
            int ih = oh - P + kh;
            if ((unsigned)ih >= (unsigned)H) continue;
            #pragma unroll
            for (int kw = 0; kw < K; ++kw) {
                int iw = ow - P + kw;
                if ((unsigned)iw >= (unsigned)W) continue;
                const u64* ap = act + ((size_t)(n * H + ih) * W + iw) * CW;
                #pragma unroll
                for (int cw = 0; cw < CW; ++cw)
                    mism += __popcll(ap[cw] ^ wreg[(kh * K + kw) * CW + cw]);
                nval++;
            }
        }
        out[((size_t)n * HW + pix) * CO + co] = (float)(nval * CI - 2 * mism) + b;
    }
}

// =================== pool(3s2) over fp32 NHWC + bn + sign -> packed ===================
// block = C threads, grid = n*OH*OW
__global__ __launch_bounds__(256) void pool_pack_nhwc(
    const float* __restrict__ in,
    const float* __restrict__ g, const float* __restrict__ cb,
    const float* __restrict__ m, const float* __restrict__ v,
    u64* __restrict__ out, int C, int H, int W, int OH, int OW) {
    int bx = blockIdx.x;
    int ow = bx % OW;
    int t = bx / OW;
    int oh = t % OH;
    int n = t / OH;
    int c = threadIdx.x;
    float mx = -INFINITY;
    #pragma unroll
    for (int kh = 0; kh < 3; ++kh)
        #pragma unroll
        for (int kw = 0; kw < 3; ++kw)
            mx = fmaxf(mx, in[((size_t)(n * H + oh * 2 + kh) * W + ow * 2 + kw) * C + c]);
    float y = bnf(mx, g[c], cb[c], m[c], v[c]);
    u64 mask = __ballot(y > 0.f);
    if ((c & 63) == 0) out[(size_t)bx * (C >> 6) + (c >> 6)] = mask;
}

// =================== bn + sign -> packed (no pool), fp32 NHWC in ===================
__global__ __launch_bounds__(384) void bn_pack_nhwc(
    const float* __restrict__ in,
    const float* __restrict__ g, const float* __restrict__ cb,
    const float* __restrict__ m, const float* __restrict__ v,
    u64* __restrict__ out, int C) {
    int bx = blockIdx.x;
    int c = threadIdx.x;
    float val = in[(size_t)bx * C + c];
    float y = bnf(val, g[c], cb[c], m[c], v[c]);
    u64 mask = __ballot(y > 0.f);
    if ((c & 63) == 0) out[(size_t)bx * (C >> 6) + (c >> 6)] = mask;
}

// =================== bn + sign -> packed for fc activations [128, 4096] ===================
__global__ __launch_bounds__(256) void bn_pack_fc(
    const float* __restrict__ in,
    const float* __restrict__ g, const float* __restrict__ cb,
    const float* __restrict__ m, const float* __restrict__ v,
    u64* __restrict__ out) {
    int c = blockIdx.x * 256 + threadIdx.x;
    int n = blockIdx.y;
    float val = in[(size_t)n * 4096 + c];
    float y = bnf(val, g[c], cb[c], m[c], v[c]);
    u64 mask = __ballot(y > 0.f);
    if ((threadIdx.x & 63) == 0) out[(size_t)n * 64 + (c >> 6)] = mask;
}

// =================== binary FC via xnor-popcount ===================
__global__ __launch_bounds__(256) void fc_bit(
    const u64* __restrict__ actw, const u64* __restrict__ wgtT,
    const float* __restrict__ bias, float* __restrict__ out, int IW, int O) {
    int o = blockIdx.x * 256 + threadIdx.x;
    if (o >= O) return;
    int n0 = blockIdx.y * 8;
    const u64* ap = actw + (size_t)n0 * IW;
    int acc[8];
    #pragma unroll
    for (int r = 0; r < 8; ++r) acc[r] = 0;
    for (int w = 0; w < IW; ++w) {
        u64 wv = wgtT[(size_t)w * O + o];
        #pragma unroll
        for (int r = 0; r < 8; ++r)
            acc[r] += __popcll(ap[(size_t)r * IW + w] ^ wv);
    }
    float b = bias[o];
    #pragma unroll
    for (int r = 0; r < 8; ++r)
        out[(size_t)(n0 + r) * O + o] = (float)(IW * 64 - 2 * acc[r]) + b;
}

// =================== BN8 + log_softmax, one block per batch row ===================
__global__ __launch_bounds__(256) void bn_lsm_kernel(
    const float* __restrict__ in,
    const float* __restrict__ g, const float* __restrict__ cb,
    const float* __restrict__ m, const float* __restrict__ v,
    float* __restrict__ out, int O) {
    int n = blockIdx.x;
    __shared__ float buf[1000];
    __shared__ float red[256];
    int tid = threadIdx.x;
    float lmax = -INFINITY;
    for (int o = tid; o < O; o += 256) {
        float y = bnf(in[(size_t)n * O + o], g[o], cb[o], m[o], v[o]);
        buf[o] = y;
        lmax = fmaxf(lmax, y);
    }
    red[tid] = lmax;
    __syncthreads();
    for (int s = 128; s > 0; s >>= 1) {
        if (tid < s) red[tid] = fmaxf(red[tid], red[tid + s]);
        __syncthreads();
    }
    float mx = red[0];
    __syncthreads();
    float lsum = 0.f;
    for (int o = tid; o < O; o += 256) lsum += expf(buf[o] - mx);
    red[tid] = lsum;
    __syncthreads();
    for (int s = 128; s > 0; s >>= 1) {
        if (tid < s) red[tid] += red[tid + s];
        __syncthreads();
    }
    float lse = mx + logf(red[0]);
    for (int o = tid; o < O; o += 256) out[(size_t)n * O + o] = buf[o] - lse;
}

extern "C" void kernel_launch(void* const* d_in, const int* in_sizes, int n_in,
                              void* d_out, int out_size, void* d_ws, size_t ws_size,
                              hipStream_t stream) {
    const float* x = (const float*)d_in[0];
    auto L = [&](int layer, int k) -> const float* {
        return (const float*)d_in[1 + (layer - 1) * 6 + k];
    };

    char* ws = (char*)d_ws;
    float* A   = (float*)(ws + 0);           // 95,551,488 fp32 NHWC scratch (max: conv2 out)
    float* Xp  = A;                          // padded input aliases A (79,847,424 B)
    u16* S1b   = (u16*)(ws + 95551488);      // [128,55,55,8] u16     6,195,200
    u16* P1u   = (u16*)(ws + 101746688);     // [128,27,27,8] u16     1,492,992
    u64* P1    = (u64*)P1u;
    u64* P2    = (u64*)(ws + 103239680);     // [128,13,13,4]           692,224
    u64* P3a   = (u64*)(ws + 103931904);     // [128,13,13,6]         1,038,336
    u64* P3b   = (u64*)(ws + 104970240);     // [128,13,13,6]         1,038,336
    u64* P5    = (u64*)(ws + 106008576);     // [128,36,4]              147,456
    u64* F7    = (u64*)(ws + 106156032);     // [128,64]                 65,536
    u64* F8    = (u64*)(ws + 106221568);     // [128,64]                 65,536
    u64* WcT2  = (u64*)(ws + 106287104);     // [5,5,2,256]             102,400
    u64* WcT3  = (u64*)(ws + 106389504);     // [3,3,4,384]             110,592
    u64* WcT4  = (u64*)(ws + 106500096);     // [3,3,6,384]             165,888
    u64* WcT5  = (u64*)(ws + 106665984);     // [3,3,6,256]             110,592
    u64* Wf6   = (u64*)(ws + 106776576);     // [144,4096]            4,718,592
    u64* Wf7   = (u64*)(ws + 111495168);     // [64,4096]             2,097,152
    u64* Wf8   = (u64*)(ws + 113592320);     // [64,1000]               512,000
    float* Wp1 = (float*)(ws + 114104320);   // [6,3,11,11,16]          139,392

    // ---- weight packs / input pad ----
    pack_w1t<<<137, 256, 0, stream>>>(L(1, 0), Wp1);
    pad_x<<<(128 * 3 * 228 * 228 + 255) / 256, 256, 0, stream>>>(x, Xp);
    pack_wc_t<5, 2><<<3200, 256, 0, stream>>>(L(2, 0), WcT2, 96, 256);
    pack_wc_t<3, 4><<<3456, 256, 0, stream>>>(L(3, 0), WcT3, 256, 384);
    pack_wc_t<3, 6><<<5184, 256, 0, stream>>>(L(4, 0), WcT4, 384, 384);
    pack_wc_t<3, 6><<<3456, 256, 0, stream>>>(L(5, 0), WcT5, 384, 256);
    pack_wfc6_t<<<4096, 256, 0, stream>>>(L(6, 0), Wf6);
    pack_wfc<<<65536, 256, 0, stream>>>(L(7, 0), Wf7, 4096);
    pack_wfc<<<16000, 256, 0, stream>>>(L(8, 0), Wf8, 1000);

    // ---- network ----
    // conv1 -> S1b u16 sign masks
    {
        dim3 g(128, 14, 6);
        conv1_tile<<<g, 256, 0, stream>>>(Xp, Wp1, L(1, 1), S1b);
    }
    // pool1 + bn1 + sign (bitwise) -> P1 [128,27,27,2 u64]
    pool1_bit<<<128 * 27, 256, 0, stream>>>(S1b, L(1, 2), L(1, 3), L(1, 4), L(1, 5), P1u);
    // conv2 (K5,P2) -> A NHWC [128,729,256]
    {
        dim3 g((729 + 7) / 8, 128);
        bconv_co<5, 2, 2, 729, 27, 256, 8, 96><<<g, 256, 0, stream>>>(P1, WcT2, L(2, 1), A);
    }
    // pool2 + bn2 + sign -> P2
    pool_pack_nhwc<<<128 * 13 * 13, 256, 0, stream>>>(A, L(2, 2), L(2, 3), L(2, 4), L(2, 5),
                                                      P2, 256, 27, 27, 13, 13);
    // conv3 -> A NHWC [128,169,384]
    {
        dim3 g((169 + 3) / 4, 128);
        bconv_co<3, 1, 4, 169, 13, 384, 4, 256><<<g, 384, 0, stream>>>(P2, WcT3, L(3, 1), A);
    }
    bn_pack_nhwc<<<128 * 169, 384, 0, stream>>>(A, L(3, 2), L(3, 3), L(3, 4), L(3, 5), P3a, 384);
    // conv4 -> A NHWC [128,169,384]
    {
        dim3 g((169 + 3) / 4, 128);
        bconv_co<3, 1, 6, 169, 13, 384, 4, 384><<<g, 384, 0, stream>>>(P3a, WcT4, L(4, 1), A);
    }
    bn_pack_nhwc<<<128 * 169, 384, 0, stream>>>(A, L(4, 2), L(4, 3), L(4, 4), L(4, 5), P3b, 384);
    // conv5 -> A NHWC [128,169,256]
    {
        dim3 g((169 + 3) / 4, 128);
        bconv_co<3, 1, 6, 169, 13, 256, 4, 384><<<g, 256, 0, stream>>>(P3b, WcT5, L(5, 1), A);
    }
    // pool5 + bn5 + sign -> P5 [128,36,4] (fc6 input)
    pool_pack_nhwc<<<128 * 6 * 6, 256, 0, stream>>>(A, L(5, 2), L(5, 3), L(5, 4), L(5, 5),
                                                    P5, 256, 13, 13, 6, 6);
    // fc6 -> A [128,4096]
    {
        dim3 g(16, 16);
        fc_bit<<<g, 256, 0, stream>>>(P5, Wf6, L(6, 1), A, 144, 4096);
    }
    {
        dim3 g(16, 128);
        bn_pack_fc<<<g, 256, 0, stream>>>(A, L(6, 2), L(6, 3), L(6, 4), L(6, 5), F7);
    }
    // fc7 -> A [128,4096]
    {
        dim3 g(16, 16);
        fc_bit<<<g, 256, 0, stream>>>(F7, Wf7, L(7, 1), A, 64, 4096);
    }
    {
        dim3 g(16, 128);
        bn_pack_fc<<<g, 256, 0, stream>>>(A, L(7, 2), L(7, 3), L(7, 4), L(7, 5), F8);
    }
    // fc8 -> A [128,1000]
    {
        dim3 g(4, 16);
        fc_bit<<<g, 256, 0, stream>>>(F8, Wf8, L(8, 1), A, 64, 1000);
    }
    // bn8 + log_softmax -> d_out
    bn_lsm_kernel<<<128, 256, 0, stream>>>(A, L(8, 2), L(8, 3), L(8, 4), L(8, 5),
                                           (float*)d_out, 1000);
}